// Round 12
// baseline (6721.476 us; speedup 1.0000x reference)
//
#include <hip/hip_runtime.h>
#include <hip/hip_fp16.h>
#include <math.h>

#define BB 512
#define HH 256
#define SS 168
#define TT 24
#define NBLK 256
#define NTHR 512
typedef unsigned long long ull;
typedef unsigned short u16;
#define BH 131072ull  // 512*256

// ---- int area (from ws): per-group SLOT flags at ib + g*4096 ----
// 64B-strided slots (16 ints), one WRITER block each, plain stores (no RMW).
//   f_e0 [0..256):    16 slots (rh*8+gi)  enc layer0, val = t+1
//   f_e1 [256..512):  16 slots (rh*8+gi)  enc layer1, val = t+1
//   f_a  [1024..1536):32 slots (m)        dec attn,   val = t+1
//   f_h0 [1536..1792):16 slots (m)        dec cell0,  val = t+1
//   f_h1 [1792..2048):16 slots (m-16)     dec cell1,  val = t+1
// ---- float offsets from fb = (float*)ws + 65536 ---- (r7/r10 map, unchanged)
// After encoder: y0 slot0 holds c0 spill; zb (h0 slot1) holds c1 spill.
#define O_Y0  0ull
#define O_H1  262144ull
#define O_H0  524288ull
#define O_CTX 786432ull   // 512 x 288 (cols 0..255 ctx, col 256 pred)
#define O_W0  933888ull   // whi0 [1024][320] bf16, wlo0 follows (163840 fl each)
#define O_W1  1261568ull  // bf16 planes [1024][512]: whi1,wlo1,dhi0,dlo0,dhi1,dlo1 (262144 fl each)
#define O_WP  2834432ull  // dec cell0 pred column [1024] f32
#define O_WDT 2835456ull  // Wd^T [256][256] f32
#define O_BP  2900992ull  // packed biases 4x1024 (e0,e1,d0,d1)
#define O_E16 2905088ull  // half[512][168][256]
#define O_P16 13915136ull // half[512][168][256]

typedef float f32x4 __attribute__((ext_vector_type(4)));
typedef float v2f __attribute__((ext_vector_type(2)));
typedef unsigned int ru4 __attribute__((ext_vector_type(4)));  // 8 bf16 raw (4 VGPR)

__device__ __forceinline__ float sigf(float x) { return 1.f / (1.f + expf(-x)); }

#define AR __ATOMIC_RELAXED
#define SCA __HIP_MEMORY_SCOPE_AGENT
__device__ __forceinline__ int aLd(const int* p) { return __hip_atomic_load(p, AR, SCA); }

// ---- UC transport: relaxed agent-scope (coherence-point) ops, no fences ----
__device__ __forceinline__ float2 ld2(const float* p) {
  ull raw = __hip_atomic_load((const ull*)p, AR, SCA);
  float2 v; v.x = __uint_as_float((unsigned)raw); v.y = __uint_as_float((unsigned)(raw >> 32));
  return v;
}
__device__ __forceinline__ float ld1(const float* p) {
  unsigned raw = __hip_atomic_load((const unsigned*)p, AR, SCA);
  return __uint_as_float(raw);
}
__device__ __forceinline__ void st1(float* p, float v) {
  __hip_atomic_store((unsigned*)p, __float_as_uint(v), AR, SCA);
}
__device__ __forceinline__ void sth(__half* p, __half v) {
  __hip_atomic_store((unsigned short*)p, __half_as_ushort(v), AR, SCA);
}
__device__ __forceinline__ void stu(unsigned* p, unsigned v) {
  __hip_atomic_store(p, v, AR, SCA);
}

// ---- manual-vmcnt loads (r0/r7-proven pattern: asm + "memory" clobber) ----
__device__ __forceinline__ void ld_h2(const float* p, v2f& a) {   // UC: 2 f32
  asm volatile("global_load_dwordx2 %0, %1, off sc0 sc1"
               : "=&v"(a) : "v"(p) : "memory");
}
__device__ __forceinline__ void ld_w2(const u16* ph, const u16* pl, ru4& h, ru4& l) {
  asm volatile("global_load_dwordx4 %0, %2, off\n\t"
               "global_load_dwordx4 %1, %3, off"
               : "=&v"(h), "=&v"(l) : "v"(ph), "v"(pl) : "memory");
}
#define VMW(n) asm volatile("s_waitcnt vmcnt(" #n ")" ::: "memory")

// inline-asm MFMA (r4/r6/r7-proven): D(=C) += A*B; VGPR C/D ok on gfx950.
#define MFMA(d, a, b) asm volatile("v_mfma_f32_16x16x32_bf16 %0, %1, %2, %0" \
                                   : "+v"(d) : "v"(a), "v"(b))
// force value materialization (compiler emits its waitcnt HERE, before our asm loads)
#define TOUCH(x) asm volatile("" : "+v"(x))

// ---- slot-flag sync: writer-exclusive slots, parallel lane polling, no RMW ----
#define SSTR 16   // slot stride in ints (64B)
__device__ __forceinline__ void arrive_slot(int* slot, int val) {
  asm volatile("s_waitcnt vmcnt(0)" ::: "memory");  // data at coherence point first
  __syncthreads();
  if (threadIdx.x == 0) __hip_atomic_store(slot, val, AR, SCA);
}
__device__ __forceinline__ void wait_slots(const int* base, int n, int tgt) {
  if (threadIdx.x < 64) {
    const int lane = threadIdx.x;
    const int* p = base + lane * SSTR;
    for (;;) {
      const int ok = (lane >= n) || (aLd(p) >= tgt);
      if (__all(ok)) break;
      __builtin_amdgcn_s_sleep(1);
    }
  }
  __syncthreads();
}
__device__ __forceinline__ void wait_slots2(const int* a, int na, const int* b, int nb, int tgt) {
  if (threadIdx.x < 64) {
    const int lane = threadIdx.x;
    const int* p = (lane < na) ? (a + lane * SSTR)
                 : (lane < na + nb) ? (b + (lane - na) * SSTR) : (const int*)nullptr;
    for (;;) {
      const int ok = (p == nullptr) || (aLd(p) >= tgt);
      if (__all(ok)) break;
      __builtin_amdgcn_s_sleep(1);
    }
  }
  __syncthreads();
}

// ---- LDS ----
struct SMT {
  union {
    struct { unsigned WsH[128][20]; unsigned WsL[128][20]; float Ht[32][36]; } m;  // mfma gemm
    struct { float As[32][65];  float Bs[32][65]; } g;   // enc_proj gemm
    struct { float h1s[256], qs[256], vs[256], sc[192], ctxs[1024], sred[4]; } at;
  };
};

__device__ __forceinline__ void fma16(float acc[4][4], const float4 hv, const float4 wv) {
  acc[0][0] += hv.x * wv.x; acc[0][1] += hv.x * wv.y; acc[0][2] += hv.x * wv.z; acc[0][3] += hv.x * wv.w;
  acc[1][0] += hv.y * wv.x; acc[1][1] += hv.y * wv.y; acc[1][2] += hv.y * wv.z; acc[1][3] += hv.y * wv.w;
  acc[2][0] += hv.z * wv.x; acc[2][1] += hv.z * wv.y; acc[2][2] += hv.z * wv.z; acc[2][3] += hv.z * wv.w;
  acc[3][0] += hv.w * wv.x; acc[3][1] += hv.w * wv.y; acc[3][2] += hv.w * wv.z; acc[3][3] += hv.w * wv.w;
}

// ---- fp32 -> bf16 hi/lo split, RNE (unbiased; dropped lo*lo ~2^-18 relative) ----
__device__ __forceinline__ unsigned rne16(unsigned u) {
  return (u + 0x7fffu + ((u >> 16) & 1u)) >> 16;
}
__device__ __forceinline__ void split8v(const f32x4 a, const f32x4 b, ru4& hi, ru4& lo) {
#pragma unroll
  for (int j = 0; j < 4; j++) {
    const float x = (j < 2) ? a[2 * j] : b[2 * j - 4];
    const float y = (j < 2) ? a[2 * j + 1] : b[2 * j - 3];
    const unsigned hx = rne16(__float_as_uint(x)), hy = rne16(__float_as_uint(y));
    const float rx = x - __uint_as_float(hx << 16);
    const float ry = y - __uint_as_float(hy << 16);
    hi[j] = (hx & 0xffffu) | (hy << 16);
    lo[j] = (rne16(__float_as_uint(rx)) & 0xffffu) | (rne16(__float_as_uint(ry)) << 16);
  }
}

// ---------------------------------------------------------------------------
// Per-chunk MFMA compute, 8-wave block (r10/r11-validated).
// ---------------------------------------------------------------------------
__device__ __forceinline__ void comp_mfma(SMT& sm, int wq, int w1, int l15, int l4,
                                          f32x4 acc[2])
{
  const int hr = w1 * 16 + l15;
  const f32x4 hv0 = *(const f32x4*)&sm.m.Ht[hr][l4 * 8];
  const f32x4 hv1 = *(const f32x4*)&sm.m.Ht[hr][l4 * 8 + 4];
  ru4 bhi, blo;
  split8v(hv0, hv1, bhi, blo);
  asm volatile("s_nop 1" : "+v"(bhi), "+v"(blo));   // VALU->MFMA RAW spacing
#pragma unroll
  for (int g = 0; g < 2; g++) {
    const int cr = wq * 32 + g * 16 + l15;
    ru4 ah = *(const ru4*)&sm.m.WsH[cr][l4 * 4];
    ru4 al = *(const ru4*)&sm.m.WsL[cr][l4 * 4];
    MFMA(acc[g], ah, bhi);
    MFMA(acc[g], ah, blo);
    MFMA(acc[g], al, bhi);
  }
}

// ---------------------------------------------------------------------------
// Software-pipelined gate-GEMM over NC 32-K chunks (r10/r11-validated).
// ---------------------------------------------------------------------------
#define STW(wh, wl) do { \
  *(ru4*)&sm.m.WsH[cgt][kt * 4] = (wh); \
  *(ru4*)&sm.m.WsL[cgt][kt * 4] = (wl); } while (0)
#define STH(a) do { \
  sm.m.Ht[r][p2 * 2] = (a)[0]; sm.m.Ht[r][p2 * 2 + 1] = (a)[1]; } while (0)

__device__ void gemm_pipe(const u16* wbh, const u16* wbl,
                          const float* hb0, const float* hb1,
                          int NC, int nc0, f32x4 acc[2], SMT& sm,
                          int wq, int w1, int l15, int l4)
{
  const int tid = threadIdx.x;
  const int r = tid & 31, p2 = tid >> 5;          // H staging coords (p2 0..15)
  const int cgt = tid & 127, kt = tid >> 7;       // W staging coords (kt 0..3)
  const float* h1p = hb1 - (ull)nc0 * 32;
#define HBk(k) (((k) < nc0) ? (hb0 + (k) * 32) : (h1p + (k) * 32))
  ru4 wh0, wl0, wh1, wl1, wh2, wl2, wh3, wl3;
  v2f h0, h1, h2, h3;
  ld_w2(wbh,      wbl,      wh0, wl0);
  ld_h2(HBk(0), h0);
  ld_w2(wbh + 32, wbl + 32, wh1, wl1);
  ld_h2(HBk(1), h1);
  ld_h2(HBk(2), h2);
  for (int c = 0; c < NC; c += 4) {
    VMW(4);
    STW(wh0, wl0); STH(h0);
    __syncthreads();
    ld_w2(wbh + (c + 2) * 32, wbl + (c + 2) * 32, wh2, wl2);
    ld_h2(HBk(c + 3), h3);
    comp_mfma(sm, wq, w1, l15, l4, acc);
    __syncthreads();
    VMW(4);
    STW(wh1, wl1); STH(h1);
    __syncthreads();
    ld_w2(wbh + (c + 3) * 32, wbl + (c + 3) * 32, wh3, wl3);
    ld_h2(HBk(c + 4), h0);
    comp_mfma(sm, wq, w1, l15, l4, acc);
    __syncthreads();
    VMW(4);
    STW(wh2, wl2); STH(h2);
    __syncthreads();
    ld_w2(wbh + (c + 4) * 32, wbl + (c + 4) * 32, wh0, wl0);
    ld_h2(HBk(c + 5), h1);
    comp_mfma(sm, wq, w1, l15, l4, acc);
    __syncthreads();
    VMW(4);
    STW(wh3, wl3); STH(h3);
    __syncthreads();
    ld_w2(wbh + (c + 5) * 32, wbl + (c + 5) * 32, wh1, wl1);
    ld_h2(HBk(c + 6), h2);
    comp_mfma(sm, wq, w1, l15, l4, acc);
    __syncthreads();
  }
  asm volatile("s_waitcnt vmcnt(0)" ::: "memory");  // junk drained before reg reuse
  asm volatile("s_nop 7\n\ts_nop 7" : "+v"(acc[0]), "+v"(acc[1]));
#undef HBk
}

// ---- epilogue: lane owns (myrow, u = ubase+g*4+l4), g<2; gates = acc[g][0..3] ----
__device__ __forceinline__ void lstm_epi2(f32x4 acc[2], float cR[2], int row, int ubase, int l4,
                                          float* hout, __half* e16, int sstep)
{
#pragma unroll
  for (int g = 0; g < 2; g++) {
    const int u = ubase + g * 4 + l4;
    const float iv = sigf(acc[g][0]), fv = sigf(acc[g][1]);
    const float gv = tanhf(acc[g][2]), ov = sigf(acc[g][3]);
    const float cn = fv * cR[g] + iv * gv;
    cR[g] = cn;
    const float hn = ov * tanhf(cn);
    st1(hout + (ull)row * 256 + u, hn);
    if (e16) sth(e16 + ((ull)row * SS + sstep) * 256 + u, __float2half(hn));
  }
}

// ---- attention + fc for one batch row (UC transport), 512-thread (r10/r11) ----
__device__ void attn_fc(int row, int t, int slot, const float* h1r, const float* wdT,
                        const float* attn_b, const float* attn_v,
                        const __half* P16, const __half* E16,
                        const float* fc_w, const float* fc_b,
                        float* ctxb, float* out, SMT& sm)
{
  const int tid = threadIdx.x;
  __syncthreads();
  if (tid < 128) {
    float2 v = ld2(h1r + (ull)slot * BH + (ull)row * 256 + tid * 2);
    sm.at.h1s[tid * 2] = v.x; sm.at.h1s[tid * 2 + 1] = v.y;
  }
  __syncthreads();
  if (t >= 1 && tid < 64) {
    float a = 0.f;
#pragma unroll
    for (int j = 0; j < 4; j++) a += sm.at.h1s[tid + 64 * j] * fc_w[tid + 64 * j];
#pragma unroll
    for (int m = 32; m >= 1; m >>= 1) a += __shfl_xor(a, m, 64);
    if (tid == 0) {
      const float p = a + fc_b[0];
      out[(ull)row * TT + (t - 1)] = p;
      st1(ctxb + (ull)row * 288 + 256, p);
    }
  }
  if (t >= TT) return;
  if (tid < 256) {
    float qv = attn_b[tid];
    for (int k = 0; k < 256; k += 4) {
      qv += sm.at.h1s[k]     * wdT[(ull)(k)     * 256 + tid];
      qv += sm.at.h1s[k + 1] * wdT[(ull)(k + 1) * 256 + tid];
      qv += sm.at.h1s[k + 2] * wdT[(ull)(k + 2) * 256 + tid];
      qv += sm.at.h1s[k + 3] * wdT[(ull)(k + 3) * 256 + tid];
    }
    sm.at.qs[tid] = qv;
    sm.at.vs[tid] = attn_v[tid];
  }
  __syncthreads();
  const int wv = tid >> 6, lane = tid & 63;
  for (int s = wv; s < SS; s += 8) {
    const __half2* Pr = (const __half2*)(P16 + ((ull)row * SS + s) * 256);
    float a = 0.f;
#pragma unroll
    for (int jj = 0; jj < 2; jj++) {
      const int i2 = lane + 64 * jj;
      const float2 pv = __half22float2(Pr[i2]);
      const int g0 = i2 * 2;
      a += sm.at.vs[g0] * tanhf(pv.x + sm.at.qs[g0]);
      a += sm.at.vs[g0 + 1] * tanhf(pv.y + sm.at.qs[g0 + 1]);
    }
#pragma unroll
    for (int m = 32; m >= 1; m >>= 1) a += __shfl_xor(a, m, 64);
    if (lane == 0) sm.at.sc[s] = a;
  }
  __syncthreads();
  if (tid < 64) {
    float m = -1e30f;
    for (int i = tid; i < SS; i += 64) m = fmaxf(m, sm.at.sc[i]);
#pragma unroll
    for (int mm = 32; mm >= 1; mm >>= 1) m = fmaxf(m, __shfl_xor(m, mm, 64));
    if (tid == 0) sm.at.sred[0] = m;
  }
  __syncthreads();
  const float smax = sm.at.sred[0];
  if (tid < SS) sm.at.sc[tid] = expf(sm.at.sc[tid] - smax);
  __syncthreads();
  if (tid < 64) {
    float ssum = 0.f;
    for (int i = tid; i < SS; i += 64) ssum += sm.at.sc[i];
#pragma unroll
    for (int mm = 32; mm >= 1; mm >>= 1) ssum += __shfl_xor(ssum, mm, 64);
    if (tid == 0) sm.at.sred[1] = ssum;
  }
  __syncthreads();
  const float rinv = 1.f / sm.at.sred[1];
  const int u2 = tid & 127, sh = tid >> 7;   // sh 0..3, 42 s each
  float cx = 0.f, cy = 0.f;
  for (int s = sh * 42; s < sh * 42 + 42; s++) {
    const float w = sm.at.sc[s] * rinv;
    const float2 ev = __half22float2(*(const __half2*)(E16 + ((ull)row * SS + s) * 256 + u2 * 2));
    cx += w * ev.x; cy += w * ev.y;
  }
  sm.at.ctxs[sh * 256 + u2 * 2] = cx;
  sm.at.ctxs[sh * 256 + u2 * 2 + 1] = cy;
  __syncthreads();
  if (tid < 256)
    st1(ctxb + (ull)row * 288 + tid,
        sm.at.ctxs[tid] + sm.at.ctxs[256 + tid] + sm.at.ctxs[512 + tid] + sm.at.ctxs[768 + tid]);
}

// ---- enc_proj 64x64 gemm tile (256-thread kernel: all active) ----
__device__ void proj_tile(const __half* E16, const float* attn_w, __half* P16,
                          int m0, int n0, SMT& sm)
{
  const int tid = threadIdx.x;
  const bool act = tid < 256;
  const int mq = tid & 15, nq = (tid >> 4) & 15;
  const int li = tid & 63, kq = (tid >> 6) & 3;
  float acc[4][4] = {{0.f}};
  for (int k0 = 0; k0 < 256; k0 += 32) {
    if (act) {
      float4 raw = *(const float4*)(E16 + (ull)(m0 + li) * 256 + k0 + kq * 8);
      const __half* hp = (const __half*)&raw;
#pragma unroll
      for (int i = 0; i < 8; i++) sm.g.As[kq * 8 + i][li] = __half2float(hp[i]);
      const float* gb = attn_w + (ull)(n0 + li) * 512 + k0 + kq * 8;
      const float4 v0 = *(const float4*)gb, v1 = *(const float4*)(gb + 4);
      sm.g.Bs[kq * 8 + 0][li] = v0.x; sm.g.Bs[kq * 8 + 1][li] = v0.y;
      sm.g.Bs[kq * 8 + 2][li] = v0.z; sm.g.Bs[kq * 8 + 3][li] = v0.w;
      sm.g.Bs[kq * 8 + 4][li] = v1.x; sm.g.Bs[kq * 8 + 5][li] = v1.y;
      sm.g.Bs[kq * 8 + 6][li] = v1.z; sm.g.Bs[kq * 8 + 7][li] = v1.w;
    }
    __syncthreads();
    if (act) {
#pragma unroll 8
      for (int kk = 0; kk < 32; kk++) {
        const float4 a4 = *(const float4*)&sm.g.As[kk][mq * 4];
        const float4 b4 = *(const float4*)&sm.g.Bs[kk][nq * 4];
        fma16(acc, a4, b4);
      }
    }
    __syncthreads();
  }
  if (act) {
#pragma unroll
    for (int i = 0; i < 4; i++) {
      const int m = m0 + mq * 4 + i;
#pragma unroll
      for (int j = 0; j < 2; j++) {
        __half2 h2; h2.x = __float2half(acc[i][j * 2]); h2.y = __float2half(acc[i][j * 2 + 1]);
        stu((unsigned*)(P16 + (ull)m * 256 + n0 + nq * 4) + j, *(unsigned*)&h2);
      }
    }
  }
}

// ===========================================================================
// KERNEL A: encoder (wavefront, slot flags). Spills c0 -> y0 slot0,
// c1 -> zb at t==SS (WAR-safe: t==SS wait guarantees layer1 done t=SS-1).
// ===========================================================================
__global__ __launch_bounds__(512, 1) void seq2seq_enc(
    const float* __restrict__ src, int* __restrict__ ib)
{
  __shared__ SMT sm;
  const int blk = blockIdx.x;
  const int tid = threadIdx.x;
  float* fb = (float*)ib + 65536;
  float* y0r  = fb + O_Y0;
  float* h1r  = fb + O_H1;
  float* h0r  = fb + O_H0;
  float* zb   = h0r + BH;
  const u16* whi0 = (const u16*)(fb + O_W0);
  const u16* wlo0 = whi0 + 1024ull * 320;
  const u16* whi1 = (const u16*)(fb + O_W1);
  const u16* wlo1 = whi1 + 1024ull * 512;
  const float* bp  = fb + O_BP;
  __half* E16 = (__half*)(fb + O_E16);
  const int g = blk >> 5, m = blk & 31;
  const int rowg = g * 64;
  int* gf = ib + g * 4096;
  int* f_e0 = gf;
  int* f_e1 = gf + 256;

  const int lm = (m < 16) ? m : (m - 16);
  const int rh = lm & 1, gi = lm >> 1;
  const int row0 = rowg + rh * 32;
  const int gc0 = gi * 128;
  const int w = tid >> 6;
  const int l15 = tid & 15, l4 = (tid >> 4) & 3;
  const int w1 = w & 1, wq = w >> 1;
  const int gcw = gc0 + wq * 32;
  const int myrow = row0 + w1 * 16 + l15;
  const int ubase = gcw >> 2;
  const int r = tid & 31;
  const int cgt = tid & 127, kt = tid >> 7;

  int* my_enc_slot = (m < 16 ? f_e0 : f_e1) + (rh * 8 + gi) * SSTR;
  const int* e0h = f_e0 + rh * 8 * SSTR;
  const int* e1h = f_e1 + rh * 8 * SSTR;

  float cReg[2] = {0.f, 0.f};

  for (int t = 0; t <= SS; t++) {
    if (t) wait_slots2(e0h, 8, e1h, 8, t);
    if (m < 16) {
      if (t < SS) {
        f32x4 acc[2];
#pragma unroll
        for (int gg = 0; gg < 2; gg++) {
          acc[gg] = *(const f32x4*)(bp + gcw + gg * 16 + l4 * 4);
          TOUCH(acc[gg]);
        }
        {
          ru4 wxh, wxl;
          ld_w2(whi0 + (ull)(gc0 + cgt) * 320 + kt * 8,
                wlo0 + (ull)(gc0 + cgt) * 320 + kt * 8, wxh, wxl);
          VMW(0);
          *(ru4*)&sm.m.WsH[cgt][kt * 4] = wxh;
          *(ru4*)&sm.m.WsL[cgt][kt * 4] = wxl;
          const int f = tid >> 5;
          sm.m.Ht[r][f]      = src[((ull)(row0 + r) * SS + t) * 16 + f];
          sm.m.Ht[r][f + 16] = 0.f;
          __syncthreads();
          comp_mfma(sm, wq, w1, l15, l4, acc);
          __syncthreads();
        }
        const float* ysrc = (t == 0) ? zb : (y0r + (ull)((t + 1) & 1) * BH);
        const float* hb0 = ysrc + (ull)(row0 + r) * 256 + (tid >> 5) * 2;
        gemm_pipe(whi0 + (ull)(gc0 + cgt) * 320 + 32 + kt * 8,
                  wlo0 + (ull)(gc0 + cgt) * 320 + 32 + kt * 8,
                  hb0, hb0, 8, 8, acc, sm, wq, w1, l15, l4);
        lstm_epi2(acc, cReg, myrow, ubase, l4, y0r + (ull)(t & 1) * BH, nullptr, 0);
      } else {
        // t == SS: spill c0 to y0 slot0 (layer1 finished t=SS-1 per the wait)
#pragma unroll
        for (int gg = 0; gg < 2; gg++)
          st1(y0r + (ull)myrow * 256 + ubase + gg * 4 + l4, cReg[gg]);
      }
    } else {
      if (t >= 1) {
        const int s = t - 1;
        f32x4 acc[2];
#pragma unroll
        for (int gg = 0; gg < 2; gg++) {
          acc[gg] = *(const f32x4*)(bp + 1024 + gcw + gg * 16 + l4 * 4);
          TOUCH(acc[gg]);
        }
        const float* ysrc = y0r + (ull)(s & 1) * BH;
        const float* hsrc = (s == 0) ? zb : (h1r + (ull)((s + 1) & 1) * BH);
        const float* hb0 = ysrc + (ull)(row0 + r) * 256 + (tid >> 5) * 2;
        const float* hb1 = hsrc + (ull)(row0 + r) * 256 + (tid >> 5) * 2;
        gemm_pipe(whi1 + (ull)(gc0 + cgt) * 512 + kt * 8,
                  wlo1 + (ull)(gc0 + cgt) * 512 + kt * 8,
                  hb0, hb1, 16, 8, acc, sm, wq, w1, l15, l4);
        lstm_epi2(acc, cReg, myrow, ubase, l4, h1r + (ull)(s & 1) * BH, E16, s);
      }
      if (t == SS) {
        // spill c1 to zb (nobody reads zb after t=1)
#pragma unroll
        for (int gg = 0; gg < 2; gg++)
          st1(zb + (ull)myrow * 256 + ubase + gg * 4 + l4, cReg[gg]);
      }
    }
    if (t < SS) arrive_slot(my_enc_slot, t + 1);
  }
  // kernel end drains all stores (device-visible before next kernel)
}

// ===========================================================================
// KERNEL B: enc_proj (256 threads, no flags; stream-ordered after encoder)
// ===========================================================================
__global__ __launch_bounds__(256, 1) void seq2seq_proj(
    const float* __restrict__ attn_w, int* __restrict__ ib)
{
  __shared__ SMT sm;
  const int blk = blockIdx.x;
  float* fb = (float*)ib + 65536;
  __half* E16 = (__half*)(fb + O_E16);
  __half* P16 = (__half*)(fb + O_P16);
  const int g = blk >> 5, m = blk & 31;
  const int em0 = g * 64 * SS;
  for (int tau = m; tau < 672; tau += 32)
    proj_tile(E16, attn_w, P16, em0 + (tau >> 2) * 64, (tau & 3) * 64, sm);
}

// ===========================================================================
// KERNEL C: decoder (slot flags f_a/f_h0/f_h1; stream-ordered after proj).
// Reloads c0 from y0 slot0, c1 from zb (UC loads).
// ===========================================================================
__global__ __launch_bounds__(512, 1) void seq2seq_dec(
    const float* __restrict__ attn_b, const float* __restrict__ attn_v,
    const float* __restrict__ fc_w, const float* __restrict__ fc_b,
    float* __restrict__ out, int* __restrict__ ib)
{
  __shared__ SMT sm;
  const int blk = blockIdx.x;
  const int tid = threadIdx.x;
  float* fb = (float*)ib + 65536;
  float* y0r  = fb + O_Y0;
  float* h1r  = fb + O_H1;
  float* h0r  = fb + O_H0;
  float* zb   = h0r + BH;
  float* ctxb = fb + O_CTX;
  const u16* whi1 = (const u16*)(fb + O_W1);
  const u16* dhi0 = whi1 + 2ull * 1024 * 512;
  const u16* dlo0 = whi1 + 3ull * 1024 * 512;
  const u16* dhi1 = whi1 + 4ull * 1024 * 512;
  const u16* dlo1 = whi1 + 5ull * 1024 * 512;
  const float* wp  = fb + O_WP;
  const float* wdT = fb + O_WDT;
  const float* bp  = fb + O_BP;
  __half* E16 = (__half*)(fb + O_E16);
  __half* P16 = (__half*)(fb + O_P16);
  const int g = blk >> 5, m = blk & 31;
  const int rowg = g * 64;
  int* gf = ib + g * 4096;
  int* f_a  = gf + 1024;
  int* f_h0 = gf + 1536;
  int* f_h1 = gf + 1792;

  const int lm = (m < 16) ? m : (m - 16);
  const int rh = lm & 1, gi = lm >> 1;
  const int row0 = rowg + rh * 32;
  const int gc0 = gi * 128;
  const int w = tid >> 6;
  const int l15 = tid & 15, l4 = (tid >> 4) & 3;
  const int w1 = w & 1, wq = w >> 1;
  const int gcw = gc0 + wq * 32;
  const int myrow = row0 + w1 * 16 + l15;
  const int ubase = gcw >> 2;
  const int r = tid & 31;
  const int cgt = tid & 127, kt = tid >> 7;

  // reload cell state spilled by the encoder
  float cReg[2];
  {
    const float* csrc = (m < 16) ? y0r : zb;
#pragma unroll
    for (int gg = 0; gg < 2; gg++)
      cReg[gg] = ld1(csrc + (ull)myrow * 256 + ubase + gg * 4 + l4);
  }

  for (int t = 0; t <= TT; t++) {
    if (t) wait_slots(f_h1, 16, t);            // cell1 step t-1 done
    const int slot = (t + 1) & 1;
    attn_fc(rowg + 2 * m,     t, slot, h1r, wdT, attn_b, attn_v, P16, E16, fc_w, fc_b, ctxb, out, sm);
    attn_fc(rowg + 2 * m + 1, t, slot, h1r, wdT, attn_b, attn_v, P16, E16, fc_w, fc_b, ctxb, out, sm);
    if (t == TT) break;
    arrive_slot(f_a + m * SSTR, t + 1);
    if (m < 16) {
      // ---- dec cell0: x = [ctx(256) | h0prev(256) | pred(1)] ----
      wait_slots(f_a, 32, t + 1);
      if (t) wait_slots(f_h0, 16, t);
      f32x4 acc[2];
#pragma unroll
      for (int gg = 0; gg < 2; gg++) {
        acc[gg] = *(const f32x4*)(bp + 2048 + gcw + gg * 16 + l4 * 4);
        TOUCH(acc[gg]);
      }
      const float* h0src = (t == 0) ? (y0r + BH) : (h0r + (ull)((t + 1) & 1) * BH);
      const float* hb0 = ctxb + (ull)(row0 + r) * 288 + (tid >> 5) * 2;
      const float* hb1 = h0src + (ull)(row0 + r) * 256 + (tid >> 5) * 2;
      gemm_pipe(dhi0 + (ull)(gc0 + cgt) * 512 + kt * 8,
                dlo0 + (ull)(gc0 + cgt) * 512 + kt * 8,
                hb0, hb1, 16, 8, acc, sm, wq, w1, l15, l4);
      const float p = ld1(ctxb + (ull)myrow * 288 + 256);
#pragma unroll
      for (int gg = 0; gg < 2; gg++) {
        const f32x4 wpv = *(const f32x4*)(wp + gcw + gg * 16 + l4 * 4);
        acc[gg] = acc[gg] + wpv * p;
      }
      lstm_epi2(acc, cReg, myrow, ubase, l4, h0r + (ull)(t & 1) * BH, nullptr, 0);
      arrive_slot(f_h0 + m * SSTR, t + 1);
    } else {
      // ---- dec cell1: x = [h0new(256) | h1prev(256)] ----
      wait_slots(f_h0, 16, t + 1);
      if (t) wait_slots(f_h1, 16, t);
      f32x4 acc[2];
#pragma unroll
      for (int gg = 0; gg < 2; gg++) {
        acc[gg] = *(const f32x4*)(bp + 3072 + gcw + gg * 16 + l4 * 4);
        TOUCH(acc[gg]);
      }
      const float* hb0 = h0r + (ull)(t & 1) * BH + (ull)(row0 + r) * 256 + (tid >> 5) * 2;
      const float* hb1 = h1r + (ull)((t + 1) & 1) * BH + (ull)(row0 + r) * 256 + (tid >> 5) * 2;
      gemm_pipe(dhi1 + (ull)(gc0 + cgt) * 512 + kt * 8,
                dlo1 + (ull)(gc0 + cgt) * 512 + kt * 8,
                hb0, hb1, 16, 8, acc, sm, wq, w1, l15, l4);
      lstm_epi2(acc, cReg, myrow, ubase, l4, h1r + (ull)(t & 1) * BH, nullptr, 0);
      arrive_slot(f_h1 + (m - 16) * SSTR, t + 1);
    }
  }
}

// ---------------------------------------------------------------------------
// Init (unchanged from r11)
// ---------------------------------------------------------------------------
__device__ __forceinline__ void split_store(float v, u16* hi, u16* lo, ull i) {
  const unsigned u = __float_as_uint(v);
  const unsigned hb = (u + 0x7fffu + ((u >> 16) & 1u)) >> 16;
  const float rr = v - __uint_as_float(hb << 16);
  const unsigned ur = __float_as_uint(rr);
  const unsigned lb = (ur + 0x7fffu + ((ur >> 16) & 1u)) >> 16;
  hi[i] = (u16)hb; lo[i] = (u16)lb;
}

__global__ void init_all(
    const float* __restrict__ src,
    const float* __restrict__ ewih0, const float* __restrict__ ewhh0, const float* __restrict__ eb0,
    const float* __restrict__ ewih1, const float* __restrict__ ewhh1, const float* __restrict__ eb1,
    const float* __restrict__ dwih0, const float* __restrict__ dwhh0, const float* __restrict__ db0,
    const float* __restrict__ dwih1, const float* __restrict__ dwhh1, const float* __restrict__ db1,
    const float* __restrict__ attn_w, int* __restrict__ ib)
{
  const int gid = blockIdx.x * 256 + threadIdx.x;
  const int NG = 1024 * 256;
  float* fb = (float*)ib + 65536;
  u16* whi0 = (u16*)(fb + O_W0);
  u16* wlo0 = whi0 + 1024ull * 320;
  u16* whi1 = (u16*)(fb + O_W1);
  u16* wlo1 = whi1 + 1024ull * 512;
  u16* dhi0 = whi1 + 2ull * 1024 * 512;
  u16* dlo0 = whi1 + 3ull * 1024 * 512;
  u16* dhi1 = whi1 + 4ull * 1024 * 512;
  u16* dlo1 = whi1 + 5ull * 1024 * 512;
  float* wpd = fb + O_WP;

  for (int i = gid; i < 32768; i += NG) ib[i] = 0;
  for (int i = gid; i < (int)BH; i += NG) fb[O_H0 + BH + i] = 0.f;   // zb
  for (int i = gid; i < 1024 * 320; i += NG) {
    const int cg = i / 320, k = i - cg * 320, j = (cg & 3) * 256 + (cg >> 2);
    float v = 0.f;
    if (k < 16) v = ewih0[(ull)j * 16 + k];
    else if (k >= 32 && k < 288) v = ewhh0[(ull)j * 256 + (k - 32)];
    split_store(v, whi0, wlo0, i);
  }
  for (int i = gid; i < 1024 * 512; i += NG) {
    const int cg = i >> 9, k = i & 511, j = (cg & 3) * 256 + (cg >> 2);
    split_store((k < 256) ? ewih1[(ull)j * 256 + k] : ewhh1[(ull)j * 256 + k - 256], whi1, wlo1, i);
    split_store((k < 256) ? dwih0[(ull)j * 257 + 1 + k] : dwhh0[(ull)j * 256 + k - 256], dhi0, dlo0, i);
    split_store((k < 256) ? dwih1[(ull)j * 256 + k] : dwhh1[(ull)j * 256 + k - 256], dhi1, dlo1, i);
  }
  for (int i = gid; i < 1024; i += NG) {
    const int j = (i & 3) * 256 + (i >> 2);
    wpd[i] = dwih0[(ull)j * 257];
  }
  for (int i = gid; i < 256 * 256; i += NG) {
    const int k = i >> 8, gg = i & 255;
    fb[O_WDT + i] = attn_w[(ull)gg * 512 + 256 + k];
  }
  for (int i = gid; i < 4096; i += NG) {
    const int set = i >> 10, cg = i & 1023, j = (cg & 3) * 256 + (cg >> 2);
    const float* bsrc = (set == 0) ? eb0 : (set == 1) ? eb1 : (set == 2) ? db0 : db1;
    fb[O_BP + i] = bsrc[j];
  }
  for (int i = gid; i < 512; i += NG)
    fb[O_CTX + (ull)i * 288 + 256] = src[((ull)i * SS + 167) * 16 + 15];
}

extern "C" void kernel_launch(void* const* d_in, const int* in_sizes, int n_in,
                              void* d_out, int out_size, void* d_ws, size_t ws_size,
                              hipStream_t stream)
{
  const float* src    = (const float*)d_in[0];
  const float* ewih0  = (const float*)d_in[1];
  const float* ewhh0  = (const float*)d_in[2];
  const float* eb0    = (const float*)d_in[3];
  const float* ewih1  = (const float*)d_in[4];
  const float* ewhh1  = (const float*)d_in[5];
  const float* eb1    = (const float*)d_in[6];
  const float* dwih0  = (const float*)d_in[7];
  const float* dwhh0  = (const float*)d_in[8];
  const float* db0    = (const float*)d_in[9];
  const float* dwih1  = (const float*)d_in[10];
  const float* dwhh1  = (const float*)d_in[11];
  const float* db1    = (const float*)d_in[12];
  const float* attn_w = (const float*)d_in[13];
  const float* attn_b = (const float*)d_in[14];
  const float* attn_v = (const float*)d_in[15];
  // d_in[16] pos_bias: post-tanh, uniform over s -> softmax-invariant, unused.
  const float* fc_w   = (const float*)d_in[17];
  const float* fc_b   = (const float*)d_in[18];
  float* out = (float*)d_out;
  int* ib    = (int*)d_ws;

  init_all<<<1024, 256, 0, stream>>>(src, ewih0, ewhh0, eb0, ewih1, ewhh1, eb1,
                                     dwih0, dwhh0, db0, dwih1, dwhh1, db1, attn_w, ib);

  // --- encoder (cooperative: 256 blocks co-resident for the flag wavefront) ---
  {
    void* args[] = { (void*)&src, (void*)&ib };
    hipError_t e = hipLaunchCooperativeKernel((const void*)seq2seq_enc,
                                              dim3(NBLK), dim3(NTHR), args, 0, stream);
    if (e != hipSuccess)
      hipLaunchKernelGGL(seq2seq_enc, dim3(NBLK), dim3(NTHR), 0, stream, src, ib);
  }
  // --- enc_proj (independent tiles, plain launch) ---
  hipLaunchKernelGGL(seq2seq_proj, dim3(NBLK), dim3(256), 0, stream, attn_w, ib);
  // --- decoder (cooperative for the flag chain) ---
  {
    void* args[] = { (void*)&attn_b, (void*)&attn_v, (void*)&fc_w, (void*)&fc_b,
                     (void*)&out, (void*)&ib };
    hipError_t e = hipLaunchCooperativeKernel((const void*)seq2seq_dec,
                                              dim3(NBLK), dim3(NTHR), args, 0, stream);
    if (e != hipSuccess)
      hipLaunchKernelGGL(seq2seq_dec, dim3(NBLK), dim3(NTHR), 0, stream,
                         attn_b, attn_v, fc_w, fc_b, out, ib);
  }
}

// Round 13
// 6671.251 us; speedup vs baseline: 1.0075x; 1.0075x over previous
//
#include <hip/hip_runtime.h>
#include <hip/hip_fp16.h>
#include <math.h>

#define BB 512
#define HH 256
#define SS 168
#define TT 24
#define NBLK 256
#define NTHR 512
typedef unsigned long long ull;
typedef unsigned short u16;
#define BH 131072ull  // 512*256

// ---- int area (from ws): per-group SLOT flags at ib + g*4096 ----
//   f_e0 [0..256):    16 slots (rh*8+gi)  enc layer0, val = t+1
//   f_e1 [256..512):  16 slots (rh*8+gi)  enc layer1, val = t+1
//   f_a  [1024..1536):32 slots (m)        dec attn,   val = t+1
//   f_h0 [1536..1792):16 slots (m)        dec cell0,  val = t+1
//   f_h1 [1792..2048):16 slots (m-16)     dec cell1,  val = t+1
// ---- float offsets from fb = (float*)ws + 65536 ---- (r7/r12 map, unchanged)
// After encoder: y0 slot0 holds c0 spill; zb (h0 slot1) holds c1 spill.
#define O_Y0  0ull
#define O_H1  262144ull
#define O_H0  524288ull
#define O_CTX 786432ull   // 512 x 288 (cols 0..255 ctx, col 256 pred)
#define O_W0  933888ull   // whi0 [1024][320] bf16, wlo0 follows (163840 fl each)
#define O_W1  1261568ull  // bf16 planes [1024][512]: whi1,wlo1,dhi0,dlo0,dhi1,dlo1 (262144 fl each)
#define O_WP  2834432ull  // dec cell0 pred column [1024] f32
#define O_WDT 2835456ull  // Wd^T [256][256] f32
#define O_BP  2900992ull  // packed biases 4x1024 (e0,e1,d0,d1)
#define O_E16 2905088ull  // half[512][168][256]
#define O_P16 13915136ull // half[512][168][256]

typedef float f32x4 __attribute__((ext_vector_type(4)));
typedef float v2f __attribute__((ext_vector_type(2)));
typedef unsigned int ru4 __attribute__((ext_vector_type(4)));  // 8 bf16/half raw (4 VGPR)

__device__ __forceinline__ float sigf(float x) { return 1.f / (1.f + expf(-x)); }

#define AR __ATOMIC_RELAXED
#define SCA __HIP_MEMORY_SCOPE_AGENT
__device__ __forceinline__ int aLd(const int* p) { return __hip_atomic_load(p, AR, SCA); }

// ---- UC transport: relaxed agent-scope (coherence-point) ops, no fences ----
__device__ __forceinline__ float2 ld2(const float* p) {
  ull raw = __hip_atomic_load((const ull*)p, AR, SCA);
  float2 v; v.x = __uint_as_float((unsigned)raw); v.y = __uint_as_float((unsigned)(raw >> 32));
  return v;
}
__device__ __forceinline__ float ld1(const float* p) {
  unsigned raw = __hip_atomic_load((const unsigned*)p, AR, SCA);
  return __uint_as_float(raw);
}
__device__ __forceinline__ void st1(float* p, float v) {
  __hip_atomic_store((unsigned*)p, __float_as_uint(v), AR, SCA);
}
// vector UC store (16B, coherence-point): state handoff within a kernel
__device__ __forceinline__ void stx4u(float* p, f32x4 v) {
  asm volatile("global_store_dwordx4 %0, %1, off sc0 sc1" :: "v"(p), "v"(v) : "memory");
}
// vector PLAIN store (16B, L2-cached): reader is in a LATER kernel only
__device__ __forceinline__ void stx4p(void* p, ru4 v) {
  asm volatile("global_store_dwordx4 %0, %1, off" :: "v"(p), "v"(v) : "memory");
}

// ---- manual-vmcnt loads (r0/r7-proven pattern: asm + "memory" clobber) ----
__device__ __forceinline__ void ld_h2(const float* p, v2f& a) {   // UC: 2 f32
  asm volatile("global_load_dwordx2 %0, %1, off sc0 sc1"
               : "=&v"(a) : "v"(p) : "memory");
}
__device__ __forceinline__ void ld_w2(const u16* ph, const u16* pl, ru4& h, ru4& l) {
  asm volatile("global_load_dwordx4 %0, %2, off\n\t"
               "global_load_dwordx4 %1, %3, off"
               : "=&v"(h), "=&v"(l) : "v"(ph), "v"(pl) : "memory");
}
#define VMW(n) asm volatile("s_waitcnt vmcnt(" #n ")" ::: "memory")

// inline-asm MFMA (r4/r6/r7-proven): D(=C) += A*B; VGPR C/D ok on gfx950.
#define MFMA(d, a, b) asm volatile("v_mfma_f32_16x16x32_bf16 %0, %1, %2, %0" \
                                   : "+v"(d) : "v"(a), "v"(b))
// force value materialization (compiler emits its waitcnt HERE, before our asm loads)
#define TOUCH(x) asm volatile("" : "+v"(x))

// ---- slot-flag sync: writer-exclusive slots, parallel lane polling, no RMW ----
#define SSTR 16   // slot stride in ints (64B)
__device__ __forceinline__ void arrive_slot(int* slot, int val) {
  asm volatile("s_waitcnt vmcnt(0)" ::: "memory");  // data at coherence point first
  __syncthreads();
  if (threadIdx.x == 0) __hip_atomic_store(slot, val, AR, SCA);
}
__device__ __forceinline__ void wait_slots(const int* base, int n, int tgt) {
  if (threadIdx.x < 64) {
    const int lane = threadIdx.x;
    const int* p = base + lane * SSTR;
    for (;;) {
      const int ok = (lane >= n) || (aLd(p) >= tgt);
      if (__all(ok)) break;
      __builtin_amdgcn_s_sleep(1);
    }
  }
  __syncthreads();
}
__device__ __forceinline__ void wait_slots2(const int* a, int na, const int* b, int nb, int tgt) {
  if (threadIdx.x < 64) {
    const int lane = threadIdx.x;
    const int* p = (lane < na) ? (a + lane * SSTR)
                 : (lane < na + nb) ? (b + (lane - na) * SSTR) : (const int*)nullptr;
    for (;;) {
      const int ok = (p == nullptr) || (aLd(p) >= tgt);
      if (__all(ok)) break;
      __builtin_amdgcn_s_sleep(1);
    }
  }
  __syncthreads();
}

// ---- LDS ----
struct SMT {
  union {
    struct { unsigned WsH[128][20]; unsigned WsL[128][20]; float Ht[32][36]; } m;  // mfma gemm
    struct { float As[32][65];  float Bs[32][65]; } g;   // enc_proj gemm
    struct { float h1s[256], qs[256], vs[256], sc[192], ctxs[1024], sred[4]; } at;
  };
};

__device__ __forceinline__ void fma16(float acc[4][4], const float4 hv, const float4 wv) {
  acc[0][0] += hv.x * wv.x; acc[0][1] += hv.x * wv.y; acc[0][2] += hv.x * wv.z; acc[0][3] += hv.x * wv.w;
  acc[1][0] += hv.y * wv.x; acc[1][1] += hv.y * wv.y; acc[1][2] += hv.y * wv.z; acc[1][3] += hv.y * wv.w;
  acc[2][0] += hv.z * wv.x; acc[2][1] += hv.z * wv.y; acc[2][2] += hv.z * wv.z; acc[2][3] += hv.z * wv.w;
  acc[3][0] += hv.w * wv.x; acc[3][1] += hv.w * wv.y; acc[3][2] += hv.w * wv.z; acc[3][3] += hv.w * wv.w;
}

// ---- fp32 -> bf16 hi/lo split, RNE (unbiased; dropped lo*lo ~2^-18 relative) ----
__device__ __forceinline__ unsigned rne16(unsigned u) {
  return (u + 0x7fffu + ((u >> 16) & 1u)) >> 16;
}
__device__ __forceinline__ void split8v(const f32x4 a, const f32x4 b, ru4& hi, ru4& lo) {
#pragma unroll
  for (int j = 0; j < 4; j++) {
    const float x = (j < 2) ? a[2 * j] : b[2 * j - 4];
    const float y = (j < 2) ? a[2 * j + 1] : b[2 * j - 3];
    const unsigned hx = rne16(__float_as_uint(x)), hy = rne16(__float_as_uint(y));
    const float rx = x - __uint_as_float(hx << 16);
    const float ry = y - __uint_as_float(hy << 16);
    hi[j] = (hx & 0xffffu) | (hy << 16);
    lo[j] = (rne16(__float_as_uint(rx)) & 0xffffu) | (rne16(__float_as_uint(ry)) << 16);
  }
}

// ---------------------------------------------------------------------------
// Per-chunk MFMA compute, 8-wave block (r10/r11-validated).
// ---------------------------------------------------------------------------
__device__ __forceinline__ void comp_mfma(SMT& sm, int wq, int w1, int l15, int l4,
                                          f32x4 acc[2])
{
  const int hr = w1 * 16 + l15;
  const f32x4 hv0 = *(const f32x4*)&sm.m.Ht[hr][l4 * 8];
  const f32x4 hv1 = *(const f32x4*)&sm.m.Ht[hr][l4 * 8 + 4];
  ru4 bhi, blo;
  split8v(hv0, hv1, bhi, blo);
  asm volatile("s_nop 1" : "+v"(bhi), "+v"(blo));   // VALU->MFMA RAW spacing
#pragma unroll
  for (int g = 0; g < 2; g++) {
    const int cr = wq * 32 + g * 16 + l15;
    ru4 ah = *(const ru4*)&sm.m.WsH[cr][l4 * 4];
    ru4 al = *(const ru4*)&sm.m.WsL[cr][l4 * 4];
    MFMA(acc[g], ah, bhi);
    MFMA(acc[g], ah, blo);
    MFMA(acc[g], al, bhi);
  }
}

// ---------------------------------------------------------------------------
// Software-pipelined gate-GEMM over NC 32-K chunks (r10/r11-validated).
// ---------------------------------------------------------------------------
#define STW(wh, wl) do { \
  *(ru4*)&sm.m.WsH[cgt][kt * 4] = (wh); \
  *(ru4*)&sm.m.WsL[cgt][kt * 4] = (wl); } while (0)
#define STH(a) do { \
  sm.m.Ht[r][p2 * 2] = (a)[0]; sm.m.Ht[r][p2 * 2 + 1] = (a)[1]; } while (0)

__device__ void gemm_pipe(const u16* wbh, const u16* wbl,
                          const float* hb0, const float* hb1,
                          int NC, int nc0, f32x4 acc[2], SMT& sm,
                          int wq, int w1, int l15, int l4)
{
  const int tid = threadIdx.x;
  const int r = tid & 31, p2 = tid >> 5;          // H staging coords (p2 0..15)
  const int cgt = tid & 127, kt = tid >> 7;       // W staging coords (kt 0..3)
  const float* h1p = hb1 - (ull)nc0 * 32;
#define HBk(k) (((k) < nc0) ? (hb0 + (k) * 32) : (h1p + (k) * 32))
  ru4 wh0, wl0, wh1, wl1, wh2, wl2, wh3, wl3;
  v2f h0, h1, h2, h3;
  ld_w2(wbh,      wbl,      wh0, wl0);
  ld_h2(HBk(0), h0);
  ld_w2(wbh + 32, wbl + 32, wh1, wl1);
  ld_h2(HBk(1), h1);
  ld_h2(HBk(2), h2);
  for (int c = 0; c < NC; c += 4) {
    VMW(4);
    STW(wh0, wl0); STH(h0);
    __syncthreads();
    ld_w2(wbh + (c + 2) * 32, wbl + (c + 2) * 32, wh2, wl2);
    ld_h2(HBk(c + 3), h3);
    comp_mfma(sm, wq, w1, l15, l4, acc);
    __syncthreads();
    VMW(4);
    STW(wh1, wl1); STH(h1);
    __syncthreads();
    ld_w2(wbh + (c + 3) * 32, wbl + (c + 3) * 32, wh3, wl3);
    ld_h2(HBk(c + 4), h0);
    comp_mfma(sm, wq, w1, l15, l4, acc);
    __syncthreads();
    VMW(4);
    STW(wh2, wl2); STH(h2);
    __syncthreads();
    ld_w2(wbh + (c + 4) * 32, wbl + (c + 4) * 32, wh0, wl0);
    ld_h2(HBk(c + 5), h1);
    comp_mfma(sm, wq, w1, l15, l4, acc);
    __syncthreads();
    VMW(4);
    STW(wh3, wl3); STH(h3);
    __syncthreads();
    ld_w2(wbh + (c + 5) * 32, wbl + (c + 5) * 32, wh1, wl1);
    ld_h2(HBk(c + 6), h2);
    comp_mfma(sm, wq, w1, l15, l4, acc);
    __syncthreads();
  }
  asm volatile("s_waitcnt vmcnt(0)" ::: "memory");  // junk drained before reg reuse
  asm volatile("s_nop 7\n\ts_nop 7" : "+v"(acc[0]), "+v"(acc[1]));
#undef HBk
}

// ---- epilogue pass 1: gates -> hn into LDS Ht[rowl][uloc]; cReg per-thread ----
__device__ __forceinline__ void epi_lds(SMT& sm, f32x4 acc[2], float cR[2],
                                        int wq, int w1, int l15, int l4)
{
  const int rowl = w1 * 16 + l15;
#pragma unroll
  for (int g = 0; g < 2; g++) {
    const float iv = sigf(acc[g][0]), fv = sigf(acc[g][1]);
    const float gv = tanhf(acc[g][2]), ov = sigf(acc[g][3]);
    const float cn = fv * cR[g] + iv * gv;
    cR[g] = cn;
    sm.m.Ht[rowl][wq * 8 + g * 4 + l4] = ov * tanhf(cn);
  }
}
// ---- epilogue pass 2a: 32x32 h slice -> vector UC stores (tid<256) ----
__device__ __forceinline__ void st_h32(SMT& sm, float* hout, int row0, int ub0) {
  const int tid = threadIdx.x;
  if (tid < 256) {
    const int rowl = tid >> 3, l8 = tid & 7;
    const f32x4 v = *(const f32x4*)&sm.m.Ht[rowl][l8 * 4];
    stx4u(hout + (ull)(row0 + rowl) * 256 + ub0 + l8 * 4, v);
  }
}
// ---- epilogue pass 2b: 32x32 h slice -> E16 halves, PLAIN stores (tid 256..384) ----
__device__ __forceinline__ void st_e16(SMT& sm, __half* E16, int row0, int ub0, int sstep) {
  const int tid = threadIdx.x;
  if (tid >= 256 && tid < 384) {
    const int t2 = tid - 256;
    const int rowl = t2 >> 2, q = t2 & 3;
    ru4 hv;
#pragma unroll
    for (int j = 0; j < 4; j++) {
      const __half a = __float2half(sm.m.Ht[rowl][q * 8 + 2 * j]);
      const __half b = __float2half(sm.m.Ht[rowl][q * 8 + 2 * j + 1]);
      hv[j] = (unsigned)__half_as_ushort(a) | ((unsigned)__half_as_ushort(b) << 16);
    }
    stx4p(E16 + ((ull)(row0 + rowl) * SS + sstep) * 256 + ub0 + q * 8, hv);
  }
}

// ---- attention + fc for one batch row (UC transport), 512-thread (r10/r11) ----
__device__ void attn_fc(int row, int t, int slot, const float* h1r, const float* wdT,
                        const float* attn_b, const float* attn_v,
                        const __half* P16, const __half* E16,
                        const float* fc_w, const float* fc_b,
                        float* ctxb, float* out, SMT& sm)
{
  const int tid = threadIdx.x;
  __syncthreads();
  if (tid < 128) {
    float2 v = ld2(h1r + (ull)slot * BH + (ull)row * 256 + tid * 2);
    sm.at.h1s[tid * 2] = v.x; sm.at.h1s[tid * 2 + 1] = v.y;
  }
  __syncthreads();
  if (t >= 1 && tid < 64) {
    float a = 0.f;
#pragma unroll
    for (int j = 0; j < 4; j++) a += sm.at.h1s[tid + 64 * j] * fc_w[tid + 64 * j];
#pragma unroll
    for (int m = 32; m >= 1; m >>= 1) a += __shfl_xor(a, m, 64);
    if (tid == 0) {
      const float p = a + fc_b[0];
      out[(ull)row * TT + (t - 1)] = p;
      st1(ctxb + (ull)row * 288 + 256, p);
    }
  }
  if (t >= TT) return;
  if (tid < 256) {
    float qv = attn_b[tid];
    for (int k = 0; k < 256; k += 4) {
      qv += sm.at.h1s[k]     * wdT[(ull)(k)     * 256 + tid];
      qv += sm.at.h1s[k + 1] * wdT[(ull)(k + 1) * 256 + tid];
      qv += sm.at.h1s[k + 2] * wdT[(ull)(k + 2) * 256 + tid];
      qv += sm.at.h1s[k + 3] * wdT[(ull)(k + 3) * 256 + tid];
    }
    sm.at.qs[tid] = qv;
    sm.at.vs[tid] = attn_v[tid];
  }
  __syncthreads();
  const int wv = tid >> 6, lane = tid & 63;
  for (int s = wv; s < SS; s += 8) {
    const __half2* Pr = (const __half2*)(P16 + ((ull)row * SS + s) * 256);
    float a = 0.f;
#pragma unroll
    for (int jj = 0; jj < 2; jj++) {
      const int i2 = lane + 64 * jj;
      const float2 pv = __half22float2(Pr[i2]);
      const int g0 = i2 * 2;
      a += sm.at.vs[g0] * tanhf(pv.x + sm.at.qs[g0]);
      a += sm.at.vs[g0 + 1] * tanhf(pv.y + sm.at.qs[g0 + 1]);
    }
#pragma unroll
    for (int m = 32; m >= 1; m >>= 1) a += __shfl_xor(a, m, 64);
    if (lane == 0) sm.at.sc[s] = a;
  }
  __syncthreads();
  if (tid < 64) {
    float m = -1e30f;
    for (int i = tid; i < SS; i += 64) m = fmaxf(m, sm.at.sc[i]);
#pragma unroll
    for (int mm = 32; mm >= 1; mm >>= 1) m = fmaxf(m, __shfl_xor(m, mm, 64));
    if (tid == 0) sm.at.sred[0] = m;
  }
  __syncthreads();
  const float smax = sm.at.sred[0];
  if (tid < SS) sm.at.sc[tid] = expf(sm.at.sc[tid] - smax);
  __syncthreads();
  if (tid < 64) {
    float ssum = 0.f;
    for (int i = tid; i < SS; i += 64) ssum += sm.at.sc[i];
#pragma unroll
    for (int mm = 32; mm >= 1; mm >>= 1) ssum += __shfl_xor(ssum, mm, 64);
    if (tid == 0) sm.at.sred[1] = ssum;
  }
  __syncthreads();
  const float rinv = 1.f / sm.at.sred[1];
  const int u2 = tid & 127, sh = tid >> 7;   // sh 0..3, 42 s each
  float cx = 0.f, cy = 0.f;
  for (int s = sh * 42; s < sh * 42 + 42; s++) {
    const float w = sm.at.sc[s] * rinv;
    const float2 ev = __half22float2(*(const __half2*)(E16 + ((ull)row * SS + s) * 256 + u2 * 2));
    cx += w * ev.x; cy += w * ev.y;
  }
  sm.at.ctxs[sh * 256 + u2 * 2] = cx;
  sm.at.ctxs[sh * 256 + u2 * 2 + 1] = cy;
  __syncthreads();
  if (tid < 256)
    st1(ctxb + (ull)row * 288 + tid,
        sm.at.ctxs[tid] + sm.at.ctxs[256 + tid] + sm.at.ctxs[512 + tid] + sm.at.ctxs[768 + tid]);
}

// ---- enc_proj 64x64 gemm tile; P16 stores PLAIN (read only by next kernel) ----
__device__ void proj_tile(const __half* E16, const float* attn_w, __half* P16,
                          int m0, int n0, SMT& sm)
{
  const int tid = threadIdx.x;
  const bool act = tid < 256;
  const int mq = tid & 15, nq = (tid >> 4) & 15;
  const int li = tid & 63, kq = (tid >> 6) & 3;
  float acc[4][4] = {{0.f}};
  for (int k0 = 0; k0 < 256; k0 += 32) {
    if (act) {
      float4 raw = *(const float4*)(E16 + (ull)(m0 + li) * 256 + k0 + kq * 8);
      const __half* hp = (const __half*)&raw;
#pragma unroll
      for (int i = 0; i < 8; i++) sm.g.As[kq * 8 + i][li] = __half2float(hp[i]);
      const float* gb = attn_w + (ull)(n0 + li) * 512 + k0 + kq * 8;
      const float4 v0 = *(const float4*)gb, v1 = *(const float4*)(gb + 4);
      sm.g.Bs[kq * 8 + 0][li] = v0.x; sm.g.Bs[kq * 8 + 1][li] = v0.y;
      sm.g.Bs[kq * 8 + 2][li] = v0.z; sm.g.Bs[kq * 8 + 3][li] = v0.w;
      sm.g.Bs[kq * 8 + 4][li] = v1.x; sm.g.Bs[kq * 8 + 5][li] = v1.y;
      sm.g.Bs[kq * 8 + 6][li] = v1.z; sm.g.Bs[kq * 8 + 7][li] = v1.w;
    }
    __syncthreads();
    if (act) {
#pragma unroll 8
      for (int kk = 0; kk < 32; kk++) {
        const float4 a4 = *(const float4*)&sm.g.As[kk][mq * 4];
        const float4 b4 = *(const float4*)&sm.g.Bs[kk][nq * 4];
        fma16(acc, a4, b4);
      }
    }
    __syncthreads();
  }
  if (act) {
#pragma unroll
    for (int i = 0; i < 4; i++) {
      const int m = m0 + mq * 4 + i;
      unsigned* dst = (unsigned*)(P16 + (ull)m * 256 + n0 + nq * 4);
#pragma unroll
      for (int j = 0; j < 2; j++) {
        __half2 h2; h2.x = __float2half(acc[i][j * 2]); h2.y = __float2half(acc[i][j * 2 + 1]);
        dst[j] = *(unsigned*)&h2;   // plain cached store
      }
    }
  }
}

// ===========================================================================
// KERNEL A: encoder (wavefront, slot flags). Spills c0 -> y0 slot0,
// c1 -> zb at t==SS (WAR-safe: t==SS wait guarantees layer1 done t=SS-1).
// ===========================================================================
__global__ __launch_bounds__(512, 1) void seq2seq_enc(
    const float* __restrict__ src, int* __restrict__ ib)
{
  __shared__ SMT sm;
  const int blk = blockIdx.x;
  const int tid = threadIdx.x;
  float* fb = (float*)ib + 65536;
  float* y0r  = fb + O_Y0;
  float* h1r  = fb + O_H1;
  float* h0r  = fb + O_H0;
  float* zb   = h0r + BH;
  const u16* whi0 = (const u16*)(fb + O_W0);
  const u16* wlo0 = whi0 + 1024ull * 320;
  const u16* whi1 = (const u16*)(fb + O_W1);
  const u16* wlo1 = whi1 + 1024ull * 512;
  const float* bp  = fb + O_BP;
  __half* E16 = (__half*)(fb + O_E16);
  const int g = blk >> 5, m = blk & 31;
  const int rowg = g * 64;
  int* gf = ib + g * 4096;
  int* f_e0 = gf;
  int* f_e1 = gf + 256;

  const int lm = (m < 16) ? m : (m - 16);
  const int rh = lm & 1, gi = lm >> 1;
  const int row0 = rowg + rh * 32;
  const int gc0 = gi * 128;
  const int ub0 = gc0 >> 2;                     // block's u base (32 u wide)
  const int w = tid >> 6;
  const int l15 = tid & 15, l4 = (tid >> 4) & 3;
  const int w1 = w & 1, wq = w >> 1;
  const int gcw = gc0 + wq * 32;
  const int myrow = row0 + w1 * 16 + l15;
  const int ubase = gcw >> 2;
  const int r = tid & 31;
  const int cgt = tid & 127, kt = tid >> 7;

  int* my_enc_slot = (m < 16 ? f_e0 : f_e1) + (rh * 8 + gi) * SSTR;
  const int* e0h = f_e0 + rh * 8 * SSTR;
  const int* e1h = f_e1 + rh * 8 * SSTR;

  float cReg[2] = {0.f, 0.f};

  for (int t = 0; t <= SS; t++) {
    if (t) wait_slots2(e0h, 8, e1h, 8, t);
    if (m < 16) {
      if (t < SS) {
        f32x4 acc[2];
#pragma unroll
        for (int gg = 0; gg < 2; gg++) {
          acc[gg] = *(const f32x4*)(bp + gcw + gg * 16 + l4 * 4);
          TOUCH(acc[gg]);
        }
        {
          ru4 wxh, wxl;
          ld_w2(whi0 + (ull)(gc0 + cgt) * 320 + kt * 8,
                wlo0 + (ull)(gc0 + cgt) * 320 + kt * 8, wxh, wxl);
          VMW(0);
          *(ru4*)&sm.m.WsH[cgt][kt * 4] = wxh;
          *(ru4*)&sm.m.WsL[cgt][kt * 4] = wxl;
          const int f = tid >> 5;
          sm.m.Ht[r][f]      = src[((ull)(row0 + r) * SS + t) * 16 + f];
          sm.m.Ht[r][f + 16] = 0.f;
          __syncthreads();
          comp_mfma(sm, wq, w1, l15, l4, acc);
          __syncthreads();
        }
        const float* ysrc = (t == 0) ? zb : (y0r + (ull)((t + 1) & 1) * BH);
        const float* hb0 = ysrc + (ull)(row0 + r) * 256 + (tid >> 5) * 2;
        gemm_pipe(whi0 + (ull)(gc0 + cgt) * 320 + 32 + kt * 8,
                  wlo0 + (ull)(gc0 + cgt) * 320 + 32 + kt * 8,
                  hb0, hb0, 8, 8, acc, sm, wq, w1, l15, l4);
        // vectorized epilogue: gates -> LDS -> 16B UC stores
        epi_lds(sm, acc, cReg, wq, w1, l15, l4);
        __syncthreads();
        st_h32(sm, y0r + (ull)(t & 1) * BH, row0, ub0);
      } else {
        // t == SS: spill c0 to y0 slot0 (layer1 finished t=SS-1 per the wait)
#pragma unroll
        for (int gg = 0; gg < 2; gg++)
          st1(y0r + (ull)myrow * 256 + ubase + gg * 4 + l4, cReg[gg]);
      }
    } else {
      if (t >= 1) {
        const int s = t - 1;
        f32x4 acc[2];
#pragma unroll
        for (int gg = 0; gg < 2; gg++) {
          acc[gg] = *(const f32x4*)(bp + 1024 + gcw + gg * 16 + l4 * 4);
          TOUCH(acc[gg]);
        }
        const float* ysrc = y0r + (ull)(s & 1) * BH;
        const float* hsrc = (s == 0) ? zb : (h1r + (ull)((s + 1) & 1) * BH);
        const float* hb0 = ysrc + (ull)(row0 + r) * 256 + (tid >> 5) * 2;
        const float* hb1 = hsrc + (ull)(row0 + r) * 256 + (tid >> 5) * 2;
        gemm_pipe(whi1 + (ull)(gc0 + cgt) * 512 + kt * 8,
                  wlo1 + (ull)(gc0 + cgt) * 512 + kt * 8,
                  hb0, hb1, 16, 8, acc, sm, wq, w1, l15, l4);
        epi_lds(sm, acc, cReg, wq, w1, l15, l4);
        __syncthreads();
        st_h32(sm, h1r + (ull)(s & 1) * BH, row0, ub0);     // UC vector
        st_e16(sm, E16, row0, ub0, s);                      // plain vector
      }
      if (t == SS) {
        // spill c1 to zb (nobody reads zb after t=1)
#pragma unroll
        for (int gg = 0; gg < 2; gg++)
          st1(zb + (ull)myrow * 256 + ubase + gg * 4 + l4, cReg[gg]);
      }
    }
    if (t < SS) arrive_slot(my_enc_slot, t + 1);
  }
}

// ===========================================================================
// KERNEL B: enc_proj (256 threads, no flags; stream-ordered after encoder)
// ===========================================================================
__global__ __launch_bounds__(256, 1) void seq2seq_proj(
    const float* __restrict__ attn_w, int* __restrict__ ib)
{
  __shared__ SMT sm;
  const int blk = blockIdx.x;
  float* fb = (float*)ib + 65536;
  __half* E16 = (__half*)(fb + O_E16);
  __half* P16 = (__half*)(fb + O_P16);
  const int g = blk >> 5, m = blk & 31;
  const int em0 = g * 64 * SS;
  for (int tau = m; tau < 672; tau += 32)
    proj_tile(E16, attn_w, P16, em0 + (tau >> 2) * 64, (tau & 3) * 64, sm);
}

// ===========================================================================
// KERNEL C: decoder (slot flags f_a/f_h0/f_h1; stream-ordered after proj).
// Reloads c0 from y0 slot0, c1 from zb (UC loads).
// ===========================================================================
__global__ __launch_bounds__(512, 1) void seq2seq_dec(
    const float* __restrict__ attn_b, const float* __restrict__ attn_v,
    const float* __restrict__ fc_w, const float* __restrict__ fc_b,
    float* __restrict__ out, int* __restrict__ ib)
{
  __shared__ SMT sm;
  const int blk = blockIdx.x;
  const int tid = threadIdx.x;
  float* fb = (float*)ib + 65536;
  float* y0r  = fb + O_Y0;
  float* h1r  = fb + O_H1;
  float* h0r  = fb + O_H0;
  float* zb   = h0r + BH;
  float* ctxb = fb + O_CTX;
  const u16* whi1 = (const u16*)(fb + O_W1);
  const u16* dhi0 = whi1 + 2ull * 1024 * 512;
  const u16* dlo0 = whi1 + 3ull * 1024 * 512;
  const u16* dhi1 = whi1 + 4ull * 1024 * 512;
  const u16* dlo1 = whi1 + 5ull * 1024 * 512;
  const float* wp  = fb + O_WP;
  const float* wdT = fb + O_WDT;
  const float* bp  = fb + O_BP;
  __half* E16 = (__half*)(fb + O_E16);
  __half* P16 = (__half*)(fb + O_P16);
  const int g = blk >> 5, m = blk & 31;
  const int rowg = g * 64;
  int* gf = ib + g * 4096;
  int* f_a  = gf + 1024;
  int* f_h0 = gf + 1536;
  int* f_h1 = gf + 1792;

  const int lm = (m < 16) ? m : (m - 16);
  const int rh = lm & 1, gi = lm >> 1;
  const int row0 = rowg + rh * 32;
  const int gc0 = gi * 128;
  const int ub0 = gc0 >> 2;
  const int w = tid >> 6;
  const int l15 = tid & 15, l4 = (tid >> 4) & 3;
  const int w1 = w & 1, wq = w >> 1;
  const int gcw = gc0 + wq * 32;
  const int myrow = row0 + w1 * 16 + l15;
  const int ubase = gcw >> 2;
  const int r = tid & 31;
  const int cgt = tid & 127, kt = tid >> 7;

  // reload cell state spilled by the encoder
  float cReg[2];
  {
    const float* csrc = (m < 16) ? y0r : zb;
#pragma unroll
    for (int gg = 0; gg < 2; gg++)
      cReg[gg] = ld1(csrc + (ull)myrow * 256 + ubase + gg * 4 + l4);
  }

  for (int t = 0; t <= TT; t++) {
    if (t) wait_slots(f_h1, 16, t);            // cell1 step t-1 done
    const int slot = (t + 1) & 1;
    attn_fc(rowg + 2 * m,     t, slot, h1r, wdT, attn_b, attn_v, P16, E16, fc_w, fc_b, ctxb, out, sm);
    attn_fc(rowg + 2 * m + 1, t, slot, h1r, wdT, attn_b, attn_v, P16, E16, fc_w, fc_b, ctxb, out, sm);
    if (t == TT) break;
    arrive_slot(f_a + m * SSTR, t + 1);
    if (m < 16) {
      // ---- dec cell0: x = [ctx(256) | h0prev(256) | pred(1)] ----
      wait_slots(f_a, 32, t + 1);
      if (t) wait_slots(f_h0, 16, t);
      f32x4 acc[2];
#pragma unroll
      for (int gg = 0; gg < 2; gg++) {
        acc[gg] = *(const f32x4*)(bp + 2048 + gcw + gg * 16 + l4 * 4);
        TOUCH(acc[gg]);
      }
      const float* h0src = (t == 0) ? (y0r + BH) : (h0r + (ull)((t + 1) & 1) * BH);
      const float* hb0 = ctxb + (ull)(row0 + r) * 288 + (tid >> 5) * 2;
      const float* hb1 = h0src + (ull)(row0 + r) * 256 + (tid >> 5) * 2;
      gemm_pipe(dhi0 + (ull)(gc0 + cgt) * 512 + kt * 8,
                dlo0 + (ull)(gc0 + cgt) * 512 + kt * 8,
                hb0, hb1, 16, 8, acc, sm, wq, w1, l15, l4);
      const float p = ld1(ctxb + (ull)myrow * 288 + 256);
#pragma unroll
      for (int gg = 0; gg < 2; gg++) {
        const f32x4 wpv = *(const f32x4*)(wp + gcw + gg * 16 + l4 * 4);
        acc[gg] = acc[gg] + wpv * p;
      }
      epi_lds(sm, acc, cReg, wq, w1, l15, l4);
      __syncthreads();
      st_h32(sm, h0r + (ull)(t & 1) * BH, row0, ub0);
      arrive_slot(f_h0 + m * SSTR, t + 1);
    } else {
      // ---- dec cell1: x = [h0new(256) | h1prev(256)] ----
      wait_slots(f_h0, 16, t + 1);
      if (t) wait_slots(f_h1, 16, t);
      f32x4 acc[2];
#pragma unroll
      for (int gg = 0; gg < 2; gg++) {
        acc[gg] = *(const f32x4*)(bp + 3072 + gcw + gg * 16 + l4 * 4);
        TOUCH(acc[gg]);
      }
      const float* hb0 = h0r + (ull)(t & 1) * BH + (ull)(row0 + r) * 256 + (tid >> 5) * 2;
      const float* hb1 = h1r + (ull)((t + 1) & 1) * BH + (ull)(row0 + r) * 256 + (tid >> 5) * 2;
      gemm_pipe(dhi1 + (ull)(gc0 + cgt) * 512 + kt * 8,
                dlo1 + (ull)(gc0 + cgt) * 512 + kt * 8,
                hb0, hb1, 16, 8, acc, sm, wq, w1, l15, l4);
      epi_lds(sm, acc, cReg, wq, w1, l15, l4);
      __syncthreads();
      st_h32(sm, h1r + (ull)(t & 1) * BH, row0, ub0);
      arrive_slot(f_h1 + (m - 16) * SSTR, t + 1);
    }
  }
}

// ---------------------------------------------------------------------------
// Init (unchanged from r12)
// ---------------------------------------------------------------------------
__device__ __forceinline__ void split_store(float v, u16* hi, u16* lo, ull i) {
  const unsigned u = __float_as_uint(v);
  const unsigned hb = (u + 0x7fffu + ((u >> 16) & 1u)) >> 16;
  const float rr = v - __uint_as_float(hb << 16);
  const unsigned ur = __float_as_uint(rr);
  const unsigned lb = (ur + 0x7fffu + ((ur >> 16) & 1u)) >> 16;
  hi[i] = (u16)hb; lo[i] = (u16)lb;
}

__global__ void init_all(
    const float* __restrict__ src,
    const float* __restrict__ ewih0, const float* __restrict__ ewhh0, const float* __restrict__ eb0,
    const float* __restrict__ ewih1, const float* __restrict__ ewhh1, const float* __restrict__ eb1,
    const float* __restrict__ dwih0, const float* __restrict__ dwhh0, const float* __restrict__ db0,
    const float* __restrict__ dwih1, const float* __restrict__ dwhh1, const float* __restrict__ db1,
    const float* __restrict__ attn_w, int* __restrict__ ib)
{
  const int gid = blockIdx.x * 256 + threadIdx.x;
  const int NG = 1024 * 256;
  float* fb = (float*)ib + 65536;
  u16* whi0 = (u16*)(fb + O_W0);
  u16* wlo0 = whi0 + 1024ull * 320;
  u16* whi1 = (u16*)(fb + O_W1);
  u16* wlo1 = whi1 + 1024ull * 512;
  u16* dhi0 = whi1 + 2ull * 1024 * 512;
  u16* dlo0 = whi1 + 3ull * 1024 * 512;
  u16* dhi1 = whi1 + 4ull * 1024 * 512;
  u16* dlo1 = whi1 + 5ull * 1024 * 512;
  float* wpd = fb + O_WP;

  for (int i = gid; i < 32768; i += NG) ib[i] = 0;
  for (int i = gid; i < (int)BH; i += NG) fb[O_H0 + BH + i] = 0.f;   // zb
  for (int i = gid; i < 1024 * 320; i += NG) {
    const int cg = i / 320, k = i - cg * 320, j = (cg & 3) * 256 + (cg >> 2);
    float v = 0.f;
    if (k < 16) v = ewih0[(ull)j * 16 + k];
    else if (k >= 32 && k < 288) v = ewhh0[(ull)j * 256 + (k - 32)];
    split_store(v, whi0, wlo0, i);
  }
  for (int i = gid; i < 1024 * 512; i += NG) {
    const int cg = i >> 9, k = i & 511, j = (cg & 3) * 256 + (cg >> 2);
    split_store((k < 256) ? ewih1[(ull)j * 256 + k] : ewhh1[(ull)j * 256 + k - 256], whi1, wlo1, i);
    split_store((k < 256) ? dwih0[(ull)j * 257 + 1 + k] : dwhh0[(ull)j * 256 + k - 256], dhi0, dlo0, i);
    split_store((k < 256) ? dwih1[(ull)j * 256 + k] : dwhh1[(ull)j * 256 + k - 256], dhi1, dlo1, i);
  }
  for (int i = gid; i < 1024; i += NG) {
    const int j = (i & 3) * 256 + (i >> 2);
    wpd[i] = dwih0[(ull)j * 257];
  }
  for (int i = gid; i < 256 * 256; i += NG) {
    const int k = i >> 8, gg = i & 255;
    fb[O_WDT + i] = attn_w[(ull)gg * 512 + 256 + k];
  }
  for (int i = gid; i < 4096; i += NG) {
    const int set = i >> 10, cg = i & 1023, j = (cg & 3) * 256 + (cg >> 2);
    const float* bsrc = (set == 0) ? eb0 : (set == 1) ? eb1 : (set == 2) ? db0 : db1;
    fb[O_BP + i] = bsrc[j];
  }
  for (int i = gid; i < 512; i += NG)
    fb[O_CTX + (ull)i * 288 + 256] = src[((ull)i * SS + 167) * 16 + 15];
}

extern "C" void kernel_launch(void* const* d_in, const int* in_sizes, int n_in,
                              void* d_out, int out_size, void* d_ws, size_t ws_size,
                              hipStream_t stream)
{
  const float* src    = (const float*)d_in[0];
  const float* ewih0  = (const float*)d_in[1];
  const float* ewhh0  = (const float*)d_in[2];
  const float* eb0    = (const float*)d_in[3];
  const float* ewih1  = (const float*)d_in[4];
  const float* ewhh1  = (const float*)d_in[5];
  const float* eb1    = (const float*)d_in[6];
  const float* dwih0  = (const float*)d_in[7];
  const float* dwhh0  = (const float*)d_in[8];
  const float* db0    = (const float*)d_in[9];
  const float* dwih1  = (const float*)d_in[10];
  const float* dwhh1  = (const float*)d_in[11];
  const float* db1    = (const float*)d_in[12];
  const float* attn_w = (const float*)d_in[13];
  const float* attn_b = (const float*)d_in[14];
  const float* attn_v = (const float*)d_in[15];
  // d_in[16] pos_bias: post-tanh, uniform over s -> softmax-invariant, unused.
  const float* fc_w   = (const float*)d_in[17];
  const float* fc_b   = (const float*)d_in[18];
  float* out = (float*)d_out;
  int* ib    = (int*)d_ws;

  init_all<<<1024, 256, 0, stream>>>(src, ewih0, ewhh0, eb0, ewih1, ewhh1, eb1,
                                     dwih0, dwhh0, db0, dwih1, dwhh1, db1, attn_w, ib);

  // --- encoder (cooperative: 256 blocks co-resident for the flag wavefront) ---
  {
    void* args[] = { (void*)&src, (void*)&ib };
    hipError_t e = hipLaunchCooperativeKernel((const void*)seq2seq_enc,
                                              dim3(NBLK), dim3(NTHR), args, 0, stream);
    if (e != hipSuccess)
      hipLaunchKernelGGL(seq2seq_enc, dim3(NBLK), dim3(NTHR), 0, stream, src, ib);
  }
  // --- enc_proj (independent tiles, plain launch) ---
  hipLaunchKernelGGL(seq2seq_proj, dim3(NBLK), dim3(256), 0, stream, attn_w, ib);
  // --- decoder (cooperative for the flag chain) ---
  {
    void* args[] = { (void*)&attn_b, (void*)&attn_v, (void*)&fc_w, (void*)&fc_b,
                     (void*)&out, (void*)&ib };
    hipError_t e = hipLaunchCooperativeKernel((const void*)seq2seq_dec,
                                              dim3(NBLK), dim3(NTHR), args, 0, stream);
    if (e != hipSuccess)
      hipLaunchKernelGGL(seq2seq_dec, dim3(NBLK), dim3(NTHR), 0, stream,
                         attn_b, attn_v, fc_w, fc_b, out, ib);
  }
}